// Round 3
// baseline (1050.336 us; speedup 1.0000x reference)
//
#include <hip/hip_runtime.h>
#include <hip/hip_bf16.h>

#define DEPTH 2
#define DIM   1024
#define SDIM  256
#define BATCH 256
#define SHOTS 64
#define M_TOT (BATCH*SHOTS)   // 16384
#define NCH   8               // scan chunks per batch
#define CH    (SHOTS/NCH)     // 8 steps per chunk

typedef __attribute__((ext_vector_type(8))) short bf16x8;  // 8 bf16 = 4 VGPRs
typedef __attribute__((ext_vector_type(4))) float f32x4;
typedef unsigned short u16;

__device__ __forceinline__ u16 f2bf(float f) {
    union { float f; unsigned u; } v; v.f = f;
    unsigned r = v.u + 0x7fffu + ((v.u >> 16) & 1u);
    return (u16)(r >> 16);
}

__device__ __forceinline__ unsigned pk_bf2(float a, float b) {
    union { __hip_bfloat162 h2; unsigned u; } c;
    c.h2 = __float22bfloat162_rn(make_float2(a, b));   // v_cvt_pk_bf16_f32
    return c.u;
}

__device__ __forceinline__ float softplus_f(float x) {
    if (x > 20.f) return x;
    return log1pf(__expf(x));
}

// async global->LDS, 16B per lane (global_load_lds_dwordx4)
__device__ __forceinline__ void gld16(const u16* g, u16* l) {
    __builtin_amdgcn_global_load_lds(
        (const __attribute__((address_space(1))) unsigned int*)g,
        (__attribute__((address_space(3))) unsigned int*)l, 16, 0, 0);
}

// ---------------------------------------------------------------------------
// transpose_conv: out[n][k] (bf16) = in[k][n] (fp32), dual-source split over n.
// ---------------------------------------------------------------------------
__global__ __launch_bounds__(256)
void transpose_conv(const float* __restrict__ A1, const float* __restrict__ A2,
                    u16* __restrict__ out, int K, int N, int SPLIT)
{
    __shared__ float T[64][65];
    const int layer = blockIdx.z;
    const int k0 = blockIdx.x * 64, n0 = blockIdx.y * 64;
    const int tid = threadIdx.x;

    const bool first = (n0 < SPLIT);
    const int scols = first ? SPLIT : (N - SPLIT);
    const float* S = (first ? A1 : A2) + (size_t)layer * K * scols
                     + (first ? n0 : (n0 - SPLIT));
    out += (size_t)layer * K * N;

    #pragma unroll
    for (int i = 0; i < 4; ++i) {
        const int c = tid + i * 256;
        const int kr = c >> 4, cc = c & 15;
        const float4 v = *(const float4*)(S + (size_t)(k0 + kr) * scols + cc * 4);
        T[kr][cc * 4 + 0] = v.x; T[kr][cc * 4 + 1] = v.y;
        T[kr][cc * 4 + 2] = v.z; T[kr][cc * 4 + 3] = v.w;
    }
    __syncthreads();
    #pragma unroll
    for (int i = 0; i < 4; ++i) {
        const int c = tid + i * 256;
        const int nr = c >> 4, cc = c & 15;
        ushort4 h;
        h.x = f2bf(T[cc * 4 + 0][nr]); h.y = f2bf(T[cc * 4 + 1][nr]);
        h.z = f2bf(T[cc * 4 + 2][nr]); h.w = f2bf(T[cc * 4 + 3][nr]);
        *(ushort4*)&out[(size_t)(n0 + nr) * K + k0 + cc * 4] = h;
    }
}

// ---------------------------------------------------------------------------
// conv_bf16: fp32 -> bf16 pack, 8 elems/thread (one-time X0 conversion).
// Also zeroes the lookback flag array (one-time; layers use distinct values).
// ---------------------------------------------------------------------------
__global__ __launch_bounds__(256)
void conv_bf16(const float* __restrict__ in, u16* __restrict__ out,
               int* __restrict__ flags, int nflags)
{
    const int t = blockIdx.x * 256 + threadIdx.x;
    if (t < nflags) flags[t] = 0;
    const size_t total = (size_t)M_TOT * DIM;
    const size_t stride = (size_t)gridDim.x * 256 * 8;
    for (size_t i = (size_t)t * 8; i < total; i += stride) {
        const float4 a = *(const float4*)(in + i);
        const float4 b = *(const float4*)(in + i + 4);
        int4 o;
        o.x = (int)pk_bf2(a.x, a.y); o.y = (int)pk_bf2(a.z, a.w);
        o.z = (int)pk_bf2(b.x, b.y); o.w = (int)pk_bf2(b.z, b.w);
        *(int4*)(out + i) = o;
    }
}

#define BM 128
#define BN 128
#define BK 32

// ---------------------------------------------------------------------------
// gemm_bf16: C[M,N] = A[M,K] @ BT[N,K]^T, bf16 MFMA 16x16x32, m97 structure:
// 128x128 tile, linear LDS [128][32], width-16 global_load_lds staging.
// EPI: 0 none, 1 +bias, 2 +bias+cs[row/64]. BF16OUT: write bf16.
// SWIZ: XCD swizzle. POOL: emit per-(batch,col) row-sums (each 128-row tile
// = 2 complete batches x 64 shots -> block-local, no atomics).
// ---------------------------------------------------------------------------
template<int EPI, bool SWIZ, bool BF16OUT, bool POOL>
__global__ __launch_bounds__(256)
void gemm_bf16(const u16* __restrict__ A, const u16* __restrict__ BT,
               void* __restrict__ Cv, const float* __restrict__ bo,
               const float* __restrict__ cs, float* __restrict__ pooled,
               int K, int ldc, int CB)
{
    __shared__ __align__(16) u16 As[BM * BK];   // 8 KiB
    __shared__ __align__(16) u16 Bs[BN * BK];   // 8 KiB

    const int tid = threadIdx.x;
    const int id  = blockIdx.x;
    int rb, cb;
    if (SWIZ) {
        const int xcd = id & 7, slot = id >> 3;
        rb = xcd + 8 * (slot / CB);
        cb = slot % CB;
    } else {
        rb = id / CB; cb = id % CB;
    }
    const int row0 = rb * BM, col0 = cb * BN;

    const int l  = tid & 63;
    const int w  = tid >> 6;
    const int wm = (w >> 1) * 64, wn = (w & 1) * 64;
    const int lr = l & 15, lq = l >> 4;

    // staging geometry: wave w covers row-groups {2w, 2w+1}, 16 rows each.
    // lane l -> row (l>>2) within group, bf16 col (l&3)*8 (16 B).
    // LDS dest = group*1024 B + l*16 B == linear row-major [128][32].
    const int sg   = w * 2;
    const int srow = l >> 2;
    const int scol = (l & 3) * 8;
    const u16* Ag = A  + (size_t)(row0 + sg * 16 + srow) * K + scol;
    const u16* Bg = BT + (size_t)(col0 + sg * 16 + srow) * K + scol;
    u16* Asd = &As[sg * 512 + l * 8];
    u16* Bsd = &Bs[sg * 512 + l * 8];

    f32x4 acc[4][4];
    #pragma unroll
    for (int i = 0; i < 4; ++i)
        #pragma unroll
        for (int j = 0; j < 4; ++j)
            acc[i][j] = (f32x4){0.f, 0.f, 0.f, 0.f};

    for (int k0 = 0; k0 < K; k0 += BK) {
        gld16(Ag + k0,                  Asd);
        gld16(Ag + (size_t)16 * K + k0, Asd + 512);
        gld16(Bg + k0,                  Bsd);
        gld16(Bg + (size_t)16 * K + k0, Bsd + 512);
        __syncthreads();

        bf16x8 af[4], bfr[4];
        #pragma unroll
        for (int i = 0; i < 4; ++i)
            af[i] = *(const bf16x8*)&As[(wm + i * 16 + lr) * BK + lq * 8];
        #pragma unroll
        for (int j = 0; j < 4; ++j)
            bfr[j] = *(const bf16x8*)&Bs[(wn + j * 16 + lr) * BK + lq * 8];

        #pragma unroll
        for (int i = 0; i < 4; ++i)
            #pragma unroll
            for (int j = 0; j < 4; ++j)
                acc[i][j] = __builtin_amdgcn_mfma_f32_16x16x32_bf16(
                    af[i], bfr[j], acc[i][j], 0, 0, 0);
        __syncthreads();
    }

    // epilogue: C/D layout col=lane&15, row=quad*4+reg
    float psum[4] = {0.f, 0.f, 0.f, 0.f};
    #pragma unroll
    for (int i = 0; i < 4; ++i) {
        const int grow = row0 + wm + i * 16 + lq * 4;
        #pragma unroll
        for (int j = 0; j < 4; ++j) {
            const int gcol = col0 + wn + j * 16 + lr;
            float addv = 0.f;
            if (EPI >= 1) addv += bo[gcol];
            if (EPI == 2) addv += cs[(size_t)(grow >> 6) * DIM + gcol];
            #pragma unroll
            for (int r = 0; r < 4; ++r) {
                const float val = acc[i][j][r] + addv;
                if (BF16OUT) ((u16*)Cv)[(size_t)(grow + r) * ldc + gcol] = f2bf(val);
                else         ((float*)Cv)[(size_t)(grow + r) * ldc + gcol] = val;
                if (POOL) psum[j] += val;
            }
        }
    }
    if (POOL) {
        // all 64 rows of this wave belong to one batch (wm fixed per wave)
        const int batch_w = (row0 + wm) >> 6;
        #pragma unroll
        for (int j = 0; j < 4; ++j) {
            float v = psum[j];
            v += __shfl_xor(v, 16, 64);   // reduce over lq (rows)
            v += __shfl_xor(v, 32, 64);
            if (lq == 0)
                pooled[(size_t)batch_w * DIM + col0 + wn + j * 16 + lr] = v;
        }
    }
}

// ---------------------------------------------------------------------------
// scan_lookback: single-pass chunked scan, decoupled lookback.
// grid (BATCH, NCH), 256 threads, 0 LDS, <=64 VGPR -> all 2048 blocks
// co-resident (32 waves/CU). Each block: compute dec/drv for its CH=8 steps
// ONCE into registers, publish per-column (prod_decay, local_h) summary,
// acquire-poll predecessor flags (independent publishes, no serial chain),
// compose prefix, replay from registers -> hsb (bf16), state (bf16).
// Flag value = layer+1 so flags need zeroing only once.
// ---------------------------------------------------------------------------
__global__ __launch_bounds__(256, 8)
void scan_lookback(const float* __restrict__ PQ,
                   const float* __restrict__ bd, const float* __restrict__ bi,
                   const float* __restrict__ A_log,
                   float2* __restrict__ sums, int* __restrict__ flags, int lval,
                   u16* __restrict__ hsb, u16* __restrict__ stateb)
{
    const int b = blockIdx.x, c = blockIdx.y, n = threadIdx.x;
    const float bdv = bd[n], biv = bi[n];
    const float spA = softplus_f(A_log[n]);
    const size_t m0 = (size_t)b * SHOTS + c * CH;
    const float* base = PQ + m0 * 512 + n;

    // load P,Q for the chunk (16 independent coalesced loads)
    float dec[CH], drv[CH];
    #pragma unroll
    for (int s = 0; s < CH; ++s) {
        dec[s] = base[s * 512];          // P
        drv[s] = base[s * 512 + SDIM];   // Q
    }
    // transform in place: dec/drv, local summary (a = prod dec, hl = local scan)
    float a = 1.f, hl = 0.f;
    #pragma unroll
    for (int s = 0; s < CH; ++s) {
        const float delta = softplus_f(dec[s] + bdv);
        const float d = __expf(-delta * spA);
        const float g = delta * (drv[s] + biv);
        dec[s] = d; drv[s] = g;
        a *= d; hl = d * hl + g;
    }

    // publish summary
    sums[((size_t)b * NCH + c) * SDIM + n] = make_float2(a, hl);
    __threadfence();
    __syncthreads();
    if (n == 0)
        __hip_atomic_store(&flags[b * NCH + c], lval, __ATOMIC_RELEASE,
                           __HIP_MEMORY_SCOPE_AGENT);

    // lookback: compose prefix from chunks 0..c-1 (each published
    // independently right after its local compute -- no serial chain)
    float h = 0.f;
    for (int j = 0; j < c; ++j) {
        while (__hip_atomic_load(&flags[b * NCH + j], __ATOMIC_ACQUIRE,
                                 __HIP_MEMORY_SCOPE_AGENT) != lval)
            __builtin_amdgcn_s_sleep(1);
        const float2 sv = sums[((size_t)b * NCH + j) * SDIM + n];
        h = sv.x * h + sv.y;
    }

    // replay from registers
    u16* hout = hsb + m0 * SDIM + n;
    #pragma unroll
    for (int s = 0; s < CH; ++s) {
        h = dec[s] * h + drv[s];
        hout[s * SDIM] = f2bf(h);
    }
    if (c == NCH - 1) stateb[(size_t)b * SDIM + n] = f2bf(h);
}

// ---------------------------------------------------------------------------
// final_kernel: pooled(sum) -> mean, + class_state, LayerNorm. ~2 MB traffic.
// ---------------------------------------------------------------------------
__global__ __launch_bounds__(1024)
void final_kernel(const float* __restrict__ pooled, const float* __restrict__ cs,
                  const float* __restrict__ gamma, const float* __restrict__ beta,
                  float* __restrict__ out)
{
    const int b = blockIdx.x;
    const int d = threadIdx.x;

    const float p = cs[(size_t)b * DIM + d]
                  + pooled[(size_t)b * DIM + d] * (1.f / SHOTS);

    __shared__ float rsum[1024], rsq[1024];
    rsum[d] = p; rsq[d] = p * p;
    __syncthreads();
    for (int off = 512; off > 0; off >>= 1) {
        if (d < off) { rsum[d] += rsum[d + off]; rsq[d] += rsq[d + off]; }
        __syncthreads();
    }
    const float mu  = rsum[0] * (1.f / DIM);
    const float var = rsq[0] * (1.f / DIM) - mu * mu;
    const float inv = rsqrtf(var + 1e-5f);

    out[(size_t)b * DIM + d] = (p - mu) * inv * gamma[d] + beta[d];
}

// ---------------------------------------------------------------------------

extern "C" void kernel_launch(void* const* d_in, const int* in_sizes, int n_in,
                              void* d_out, int out_size, void* d_ws, size_t ws_size,
                              hipStream_t stream)
{
    const float* X0    = (const float*)d_in[0];
    const float* Wd    = (const float*)d_in[1];
    const float* bd    = (const float*)d_in[2];
    const float* Wi    = (const float*)d_in[3];
    const float* bi    = (const float*)d_in[4];
    const float* A_log = (const float*)d_in[5];
    const float* Wo    = (const float*)d_in[6];
    const float* bo    = (const float*)d_in[7];
    const float* Ws    = (const float*)d_in[8];
    const float* bs    = (const float*)d_in[9];
    const float* gamma = (const float*)d_in[10];
    const float* beta  = (const float*)d_in[11];

    float* out_cr     = (float*)d_out;                  // [BATCH, DIM]
    float* out_hidden = out_cr + (size_t)BATCH * DIM;   // [BATCH, SHOTS, DIM] fp32

    // Xbf (bf16 activations) lives in the out_hidden region as scratch; it is
    // dead before the layer-1 hidden GEMM performs the fp32 out_hidden write.
    u16* Xbf = (u16*)out_hidden;

    // ws layout: 51,519,488 B <= proven 51,642,368 B footprint.
    // pooled ALIASES sums: sums is dead after the layer-1 scan completes;
    // pooled is written only by the layer-1 hidden GEMM (later on the stream).
    char* w = (char*)d_ws;
    float*  PQ     = (float*)w;  w += (size_t)M_TOT * 512 * 4;          // 33.55 MB
    float2* sums   = (float2*)w; w += (size_t)BATCH * NCH * SDIM * 8;   //  4.19 MB
    float*  pooled = (float*)sums;                                      //  (alias)
    float*  csbuf  = (float*)w;  w += (size_t)BATCH * DIM * 4;          //  1.05 MB
    u16*    stateb = (u16*)w;    w += (size_t)BATCH * SDIM * 2;         //  0.13 MB
    u16*    hsb    = (u16*)w;    w += (size_t)M_TOT * SDIM * 2;         //  8.39 MB
    u16*    WcombT = (u16*)w;    w += (size_t)DEPTH * 512 * 1024 * 2;   //  2.10 MB
    u16*    WoT    = (u16*)w;    w += (size_t)DEPTH * 1024 * 256 * 2;   //  1.05 MB
    u16*    WsT    = (u16*)w;    w += (size_t)DEPTH * 1024 * 256 * 2;   //  1.05 MB
    int*    flags  = (int*)w;    w += (size_t)BATCH * NCH * 4;          //  8 KB

    // one-time weight transpose+convert
    transpose_conv<<<dim3(1024 / 64, 512 / 64, DEPTH), 256, 0, stream>>>(
        Wd, Wi, WcombT, 1024, 512, 256);   // rows 0-255: WdT, 256-511: WiT
    transpose_conv<<<dim3(256 / 64, 1024 / 64, DEPTH), 256, 0, stream>>>(
        Wo, Wo, WoT, 256, 1024, 1024);
    transpose_conv<<<dim3(256 / 64, 1024 / 64, DEPTH), 256, 0, stream>>>(
        Ws, Ws, WsT, 256, 1024, 1024);
    // one-time input conversion fp32 -> bf16 (+ flag zeroing)
    conv_bf16<<<2048, 256, 0, stream>>>(X0, Xbf, flags, BATCH * NCH);

    for (int l = 0; l < DEPTH; ++l) {
        // PQ = Xbf @ [Wd|Wi]  (M=16384, N=512, K=1024)
        gemm_bf16<0, true, false, false><<<512, 256, 0, stream>>>(
            Xbf, WcombT + (size_t)l * 512 * 1024, PQ, nullptr, nullptr, nullptr,
            1024, 512, 4);
        // single-pass chunked scan with decoupled lookback
        scan_lookback<<<dim3(BATCH, NCH), 256, 0, stream>>>(
            PQ, bd + l * SDIM, bi + l * SDIM, A_log + l * SDIM,
            sums, flags, l + 1, hsb, stateb);
        // class_state = state @ Ws + bs  (M=256, N=1024, K=256)
        gemm_bf16<1, false, false, false><<<16, 256, 0, stream>>>(
            stateb, WsT + (size_t)l * 1024 * 256, csbuf, bs + l * DIM, nullptr,
            nullptr, 256, 1024, 8);
        // hidden = hs @ Wo + bo + class_state  (M=16384, N=1024, K=256)
        if (l < DEPTH - 1) {
            gemm_bf16<2, true, true, false><<<1024, 256, 0, stream>>>(
                hsb, WoT + (size_t)l * 1024 * 256, Xbf, bo + l * DIM, csbuf,
                nullptr, 256, 1024, 8);
        } else {
            gemm_bf16<2, true, false, true><<<1024, 256, 0, stream>>>(
                hsb, WoT + (size_t)l * 1024 * 256, out_hidden, bo + l * DIM, csbuf,
                pooled, 256, 1024, 8);
        }
    }
    final_kernel<<<BATCH, 1024, 0, stream>>>(pooled, csbuf, gamma, beta, out_cr);
}

// Round 4
// 299.657 us; speedup vs baseline: 3.5051x; 3.5051x over previous
//
#include <hip/hip_runtime.h>
#include <hip/hip_bf16.h>

#define DEPTH 2
#define DIM   1024
#define SDIM  256
#define BATCH 256
#define SHOTS 64
#define M_TOT (BATCH*SHOTS)   // 16384
#define SGRP  4               // scan groups per batch
#define GSTEP (SHOTS/SGRP)    // 16 steps per group

typedef __attribute__((ext_vector_type(8))) short bf16x8;  // 8 bf16 = 4 VGPRs
typedef __attribute__((ext_vector_type(4))) float f32x4;
typedef unsigned short u16;

__device__ __forceinline__ u16 f2bf(float f) {
    union { float f; unsigned u; } v; v.f = f;
    unsigned r = v.u + 0x7fffu + ((v.u >> 16) & 1u);
    return (u16)(r >> 16);
}

__device__ __forceinline__ unsigned pk_bf2(float a, float b) {
    union { __hip_bfloat162 h2; unsigned u; } c;
    c.h2 = __float22bfloat162_rn(make_float2(a, b));   // v_cvt_pk_bf16_f32
    return c.u;
}

__device__ __forceinline__ float softplus_f(float x) {
    if (x > 20.f) return x;
    return log1pf(__expf(x));
}

// async global->LDS, 16B per lane (global_load_lds_dwordx4)
__device__ __forceinline__ void gld16(const u16* g, u16* l) {
    __builtin_amdgcn_global_load_lds(
        (const __attribute__((address_space(1))) unsigned int*)g,
        (__attribute__((address_space(3))) unsigned int*)l, 16, 0, 0);
}

// ---------------------------------------------------------------------------
// transpose_conv: out[n][k] (bf16) = in[k][n] (fp32), dual-source split over n.
// ---------------------------------------------------------------------------
__global__ __launch_bounds__(256)
void transpose_conv(const float* __restrict__ A1, const float* __restrict__ A2,
                    u16* __restrict__ out, int K, int N, int SPLIT)
{
    __shared__ float T[64][65];
    const int layer = blockIdx.z;
    const int k0 = blockIdx.x * 64, n0 = blockIdx.y * 64;
    const int tid = threadIdx.x;

    const bool first = (n0 < SPLIT);
    const int scols = first ? SPLIT : (N - SPLIT);
    const float* S = (first ? A1 : A2) + (size_t)layer * K * scols
                     + (first ? n0 : (n0 - SPLIT));
    out += (size_t)layer * K * N;

    #pragma unroll
    for (int i = 0; i < 4; ++i) {
        const int c = tid + i * 256;
        const int kr = c >> 4, cc = c & 15;
        const float4 v = *(const float4*)(S + (size_t)(k0 + kr) * scols + cc * 4);
        T[kr][cc * 4 + 0] = v.x; T[kr][cc * 4 + 1] = v.y;
        T[kr][cc * 4 + 2] = v.z; T[kr][cc * 4 + 3] = v.w;
    }
    __syncthreads();
    #pragma unroll
    for (int i = 0; i < 4; ++i) {
        const int c = tid + i * 256;
        const int nr = c >> 4, cc = c & 15;
        ushort4 h;
        h.x = f2bf(T[cc * 4 + 0][nr]); h.y = f2bf(T[cc * 4 + 1][nr]);
        h.z = f2bf(T[cc * 4 + 2][nr]); h.w = f2bf(T[cc * 4 + 3][nr]);
        *(ushort4*)&out[(size_t)(n0 + nr) * K + k0 + cc * 4] = h;
    }
}

// ---------------------------------------------------------------------------
// conv_bf16: fp32 -> bf16 pack, 8 elems/thread (one-time X0 conversion).
// ---------------------------------------------------------------------------
__global__ __launch_bounds__(256)
void conv_bf16(const float* __restrict__ in, u16* __restrict__ out)
{
    const size_t total = (size_t)M_TOT * DIM;
    const size_t stride = (size_t)gridDim.x * 256 * 8;
    for (size_t i = ((size_t)blockIdx.x * 256 + threadIdx.x) * 8; i < total; i += stride) {
        const float4 a = *(const float4*)(in + i);
        const float4 b = *(const float4*)(in + i + 4);
        int4 o;
        o.x = (int)pk_bf2(a.x, a.y); o.y = (int)pk_bf2(a.z, a.w);
        o.z = (int)pk_bf2(b.x, b.y); o.w = (int)pk_bf2(b.z, b.w);
        *(int4*)(out + i) = o;
    }
}

#define BM 128
#define BN 128
#define BK 32

// ---------------------------------------------------------------------------
// gemm_bf16: C[M,N] = A[M,K] @ BT[N,K]^T, bf16 MFMA 16x16x32, m97 structure:
// 128x128 tile, linear LDS [128][32], width-16 global_load_lds staging.
// EPI: 0 none, 1 +bias, 2 +bias+cs[row/64]. BF16OUT: write bf16.
// SWIZ: XCD swizzle. POOL: emit per-(batch,col) row-sums (each 128-row tile
// = 2 complete batches x 64 shots -> block-local, no atomics).
// ---------------------------------------------------------------------------
template<int EPI, bool SWIZ, bool BF16OUT, bool POOL>
__global__ __launch_bounds__(256)
void gemm_bf16(const u16* __restrict__ A, const u16* __restrict__ BT,
               void* __restrict__ Cv, const float* __restrict__ bo,
               const float* __restrict__ cs, float* __restrict__ pooled,
               int K, int ldc, int CB)
{
    __shared__ __align__(16) u16 As[BM * BK];   // 8 KiB
    __shared__ __align__(16) u16 Bs[BN * BK];   // 8 KiB

    const int tid = threadIdx.x;
    const int id  = blockIdx.x;
    int rb, cb;
    if (SWIZ) {
        const int xcd = id & 7, slot = id >> 3;
        rb = xcd + 8 * (slot / CB);
        cb = slot % CB;
    } else {
        rb = id / CB; cb = id % CB;
    }
    const int row0 = rb * BM, col0 = cb * BN;

    const int l  = tid & 63;
    const int w  = tid >> 6;
    const int wm = (w >> 1) * 64, wn = (w & 1) * 64;
    const int lr = l & 15, lq = l >> 4;

    // staging geometry: wave w covers row-groups {2w, 2w+1}, 16 rows each.
    // lane l -> row (l>>2) within group, bf16 col (l&3)*8 (16 B).
    // LDS dest = group*1024 B + l*16 B == linear row-major [128][32].
    const int sg   = w * 2;
    const int srow = l >> 2;
    const int scol = (l & 3) * 8;
    const u16* Ag = A  + (size_t)(row0 + sg * 16 + srow) * K + scol;
    const u16* Bg = BT + (size_t)(col0 + sg * 16 + srow) * K + scol;
    u16* Asd = &As[sg * 512 + l * 8];
    u16* Bsd = &Bs[sg * 512 + l * 8];

    f32x4 acc[4][4];
    #pragma unroll
    for (int i = 0; i < 4; ++i)
        #pragma unroll
        for (int j = 0; j < 4; ++j)
            acc[i][j] = (f32x4){0.f, 0.f, 0.f, 0.f};

    for (int k0 = 0; k0 < K; k0 += BK) {
        gld16(Ag + k0,                  Asd);
        gld16(Ag + (size_t)16 * K + k0, Asd + 512);
        gld16(Bg + k0,                  Bsd);
        gld16(Bg + (size_t)16 * K + k0, Bsd + 512);
        __syncthreads();

        bf16x8 af[4], bfr[4];
        #pragma unroll
        for (int i = 0; i < 4; ++i)
            af[i] = *(const bf16x8*)&As[(wm + i * 16 + lr) * BK + lq * 8];
        #pragma unroll
        for (int j = 0; j < 4; ++j)
            bfr[j] = *(const bf16x8*)&Bs[(wn + j * 16 + lr) * BK + lq * 8];

        #pragma unroll
        for (int i = 0; i < 4; ++i)
            #pragma unroll
            for (int j = 0; j < 4; ++j)
                acc[i][j] = __builtin_amdgcn_mfma_f32_16x16x32_bf16(
                    af[i], bfr[j], acc[i][j], 0, 0, 0);
        __syncthreads();
    }

    // epilogue: C/D layout col=lane&15, row=quad*4+reg
    float psum[4] = {0.f, 0.f, 0.f, 0.f};
    #pragma unroll
    for (int i = 0; i < 4; ++i) {
        const int grow = row0 + wm + i * 16 + lq * 4;
        #pragma unroll
        for (int j = 0; j < 4; ++j) {
            const int gcol = col0 + wn + j * 16 + lr;
            float addv = 0.f;
            if (EPI >= 1) addv += bo[gcol];
            if (EPI == 2) addv += cs[(size_t)(grow >> 6) * DIM + gcol];
            #pragma unroll
            for (int r = 0; r < 4; ++r) {
                const float val = acc[i][j][r] + addv;
                if (BF16OUT) ((u16*)Cv)[(size_t)(grow + r) * ldc + gcol] = f2bf(val);
                else         ((float*)Cv)[(size_t)(grow + r) * ldc + gcol] = val;
                if (POOL) psum[j] += val;
            }
        }
    }
    if (POOL) {
        // all 64 rows of this wave belong to one batch (wm fixed per wave)
        const int batch_w = (row0 + wm) >> 6;
        #pragma unroll
        for (int j = 0; j < 4; ++j) {
            float v = psum[j];
            v += __shfl_xor(v, 16, 64);   // reduce over lq (rows)
            v += __shfl_xor(v, 32, 64);
            if (lq == 0)
                pooled[(size_t)batch_w * DIM + col0 + wn + j * 16 + lr] = v;
        }
    }
}

// ---------------------------------------------------------------------------
// scan_batch: intra-block chunked scan, NO cross-block communication.
// grid (BATCH, 2): block owns (batch, 128-col half). 512 threads = 4 groups
// x 128 cols; each group computes dec/drv for its 16 steps ONCE into regs,
// publishes (prod_dec, local_h) to LDS, __syncthreads, composes <=3-term
// prefix, replays from regs -> hsb (bf16), state (bf16).
// PQ read once, transcendentals once. 4 blocks/CU -> 32 waves/CU.
// ---------------------------------------------------------------------------
__global__ __launch_bounds__(512, 8)
void scan_batch(const float* __restrict__ PQ,
                const float* __restrict__ bd, const float* __restrict__ bi,
                const float* __restrict__ A_log,
                u16* __restrict__ hsb, u16* __restrict__ stateb)
{
    const int b  = blockIdx.x;
    const int nc = threadIdx.x & 127;              // col within half
    const int n  = nc + (blockIdx.y << 7);         // 0..255
    const int g  = threadIdx.x >> 7;               // group 0..3
    const float bdv = bd[n], biv = bi[n];
    const float spA = softplus_f(A_log[n]);
    const size_t m0 = (size_t)b * SHOTS + g * GSTEP;
    const float* base = PQ + m0 * 512 + n;

    // load the group's P,Q (32 independent coalesced loads)
    float dec[GSTEP], drv[GSTEP];
    #pragma unroll
    for (int s = 0; s < GSTEP; ++s) {
        dec[s] = base[s * 512];          // P
        drv[s] = base[s * 512 + SDIM];   // Q
    }
    // transform once: dec/drv + local summary (a = prod dec, hl = local scan)
    float a = 1.f, hl = 0.f;
    #pragma unroll
    for (int s = 0; s < GSTEP; ++s) {
        const float delta = softplus_f(dec[s] + bdv);
        const float d  = __expf(-delta * spA);
        const float gv = delta * (drv[s] + biv);
        dec[s] = d; drv[s] = gv;
        a *= d; hl = d * hl + gv;
    }

    __shared__ float2 grp[SGRP][128];
    grp[g][nc] = make_float2(a, hl);
    __syncthreads();

    // prefix over earlier groups (uniform-per-wave trip count)
    float h = 0.f;
    for (int j = 0; j < g; ++j) {
        const float2 sv = grp[j][nc];
        h = sv.x * h + sv.y;
    }

    // replay from registers
    u16* hout = hsb + m0 * SDIM + n;
    #pragma unroll
    for (int s = 0; s < GSTEP; ++s) {
        h = dec[s] * h + drv[s];
        hout[s * SDIM] = f2bf(h);
    }
    if (g == SGRP - 1) stateb[(size_t)b * SDIM + n] = f2bf(h);
}

// ---------------------------------------------------------------------------
// final_kernel: pooled(sum) -> mean, + class_state, LayerNorm. ~2 MB traffic.
// ---------------------------------------------------------------------------
__global__ __launch_bounds__(1024)
void final_kernel(const float* __restrict__ pooled, const float* __restrict__ cs,
                  const float* __restrict__ gamma, const float* __restrict__ beta,
                  float* __restrict__ out)
{
    const int b = blockIdx.x;
    const int d = threadIdx.x;

    const float p = cs[(size_t)b * DIM + d]
                  + pooled[(size_t)b * DIM + d] * (1.f / SHOTS);

    __shared__ float rsum[1024], rsq[1024];
    rsum[d] = p; rsq[d] = p * p;
    __syncthreads();
    for (int off = 512; off > 0; off >>= 1) {
        if (d < off) { rsum[d] += rsum[d + off]; rsq[d] += rsq[d + off]; }
        __syncthreads();
    }
    const float mu  = rsum[0] * (1.f / DIM);
    const float var = rsq[0] * (1.f / DIM) - mu * mu;
    const float inv = rsqrtf(var + 1e-5f);

    out[(size_t)b * DIM + d] = (p - mu) * inv * gamma[d] + beta[d];
}

// ---------------------------------------------------------------------------

extern "C" void kernel_launch(void* const* d_in, const int* in_sizes, int n_in,
                              void* d_out, int out_size, void* d_ws, size_t ws_size,
                              hipStream_t stream)
{
    const float* X0    = (const float*)d_in[0];
    const float* Wd    = (const float*)d_in[1];
    const float* bd    = (const float*)d_in[2];
    const float* Wi    = (const float*)d_in[3];
    const float* bi    = (const float*)d_in[4];
    const float* A_log = (const float*)d_in[5];
    const float* Wo    = (const float*)d_in[6];
    const float* bo    = (const float*)d_in[7];
    const float* Ws    = (const float*)d_in[8];
    const float* bs    = (const float*)d_in[9];
    const float* gamma = (const float*)d_in[10];
    const float* beta  = (const float*)d_in[11];

    float* out_cr     = (float*)d_out;                  // [BATCH, DIM]
    float* out_hidden = out_cr + (size_t)BATCH * DIM;   // [BATCH, SHOTS, DIM] fp32

    // Xbf (bf16 activations) lives in the out_hidden region as scratch; it is
    // dead before the layer-1 hidden GEMM performs the fp32 out_hidden write.
    u16* Xbf = (u16*)out_hidden;

    // ws layout: ~48.4 MB <= proven 51.6 MB footprint
    char* w = (char*)d_ws;
    float*  PQ     = (float*)w;  w += (size_t)M_TOT * 512 * 4;          // 33.55 MB
    float*  csbuf  = (float*)w;  w += (size_t)BATCH * DIM * 4;          //  1.05 MB
    float*  pooled = (float*)w;  w += (size_t)BATCH * DIM * 4;          //  1.05 MB
    u16*    stateb = (u16*)w;    w += (size_t)BATCH * SDIM * 2;         //  0.13 MB
    u16*    hsb    = (u16*)w;    w += (size_t)M_TOT * SDIM * 2;         //  8.39 MB
    u16*    WcombT = (u16*)w;    w += (size_t)DEPTH * 512 * 1024 * 2;   //  2.10 MB
    u16*    WoT    = (u16*)w;    w += (size_t)DEPTH * 1024 * 256 * 2;   //  1.05 MB
    u16*    WsT    = (u16*)w;    w += (size_t)DEPTH * 1024 * 256 * 2;   //  1.05 MB

    // one-time weight transpose+convert
    transpose_conv<<<dim3(1024 / 64, 512 / 64, DEPTH), 256, 0, stream>>>(
        Wd, Wi, WcombT, 1024, 512, 256);   // rows 0-255: WdT, 256-511: WiT
    transpose_conv<<<dim3(256 / 64, 1024 / 64, DEPTH), 256, 0, stream>>>(
        Wo, Wo, WoT, 256, 1024, 1024);
    transpose_conv<<<dim3(256 / 64, 1024 / 64, DEPTH), 256, 0, stream>>>(
        Ws, Ws, WsT, 256, 1024, 1024);
    // one-time input conversion fp32 -> bf16
    conv_bf16<<<2048, 256, 0, stream>>>(X0, Xbf);

    for (int l = 0; l < DEPTH; ++l) {
        // PQ = Xbf @ [Wd|Wi]  (M=16384, N=512, K=1024)
        gemm_bf16<0, true, false, false><<<512, 256, 0, stream>>>(
            Xbf, WcombT + (size_t)l * 512 * 1024, PQ, nullptr, nullptr, nullptr,
            1024, 512, 4);
        // intra-block chunked scan (PQ read once, no cross-block sync)
        scan_batch<<<dim3(BATCH, 2), 512, 0, stream>>>(
            PQ, bd + l * SDIM, bi + l * SDIM, A_log + l * SDIM, hsb, stateb);
        // class_state = state @ Ws + bs  (M=256, N=1024, K=256)
        gemm_bf16<1, false, false, false><<<16, 256, 0, stream>>>(
            stateb, WsT + (size_t)l * 1024 * 256, csbuf, bs + l * DIM, nullptr,
            nullptr, 256, 1024, 8);
        // hidden = hs @ Wo + bo + class_state  (M=16384, N=1024, K=256)
        if (l < DEPTH - 1) {
            gemm_bf16<2, true, true, false><<<1024, 256, 0, stream>>>(
                hsb, WoT + (size_t)l * 1024 * 256, Xbf, bo + l * DIM, csbuf,
                nullptr, 256, 1024, 8);
        } else {
            gemm_bf16<2, true, false, true><<<1024, 256, 0, stream>>>(
                hsb, WoT + (size_t)l * 1024 * 256, out_hidden, bo + l * DIM, csbuf,
                pooled, 256, 1024, 8);
        }
    }
    final_kernel<<<BATCH, 1024, 0, stream>>>(pooled, csbuf, gamma, beta, out_cr);
}

// Round 5
// 296.452 us; speedup vs baseline: 3.5430x; 1.0108x over previous
//
#include <hip/hip_runtime.h>
#include <hip/hip_bf16.h>

#define DEPTH 2
#define DIM   1024
#define SDIM  256
#define BATCH 256
#define SHOTS 64
#define M_TOT (BATCH*SHOTS)   // 16384
#define SGRP  4               // scan groups per batch
#define GSTEP (SHOTS/SGRP)    // 16 steps per group

typedef __attribute__((ext_vector_type(8))) short bf16x8;  // 8 bf16 = 4 VGPRs
typedef __attribute__((ext_vector_type(4))) float f32x4;
typedef unsigned short u16;

__device__ __forceinline__ u16 f2bf(float f) {
    union { float f; unsigned u; } v; v.f = f;
    unsigned r = v.u + 0x7fffu + ((v.u >> 16) & 1u);
    return (u16)(r >> 16);
}

__device__ __forceinline__ unsigned pk_bf2(float a, float b) {
    union { __hip_bfloat162 h2; unsigned u; } c;
    c.h2 = __float22bfloat162_rn(make_float2(a, b));   // v_cvt_pk_bf16_f32
    return c.u;
}

__device__ __forceinline__ float bf2f(u16 h) {
    union { unsigned u; float f; } c; c.u = (unsigned)h << 16; return c.f;
}

__device__ __forceinline__ float softplus_f(float x) {
    if (x > 20.f) return x;
    return log1pf(__expf(x));
}

// async global->LDS, 16B per lane (global_load_lds_dwordx4)
__device__ __forceinline__ void gld16(const u16* g, u16* l) {
    __builtin_amdgcn_global_load_lds(
        (const __attribute__((address_space(1))) unsigned int*)g,
        (__attribute__((address_space(3))) unsigned int*)l, 16, 0, 0);
}

// ---------------------------------------------------------------------------
// transpose body: out[n][k] (bf16) = in[k][n] (fp32), 64x64 tile via LDS.
// ---------------------------------------------------------------------------
__device__ __forceinline__ void transpose_body(
    float T[64][65], const float* __restrict__ A1, const float* __restrict__ A2,
    u16* __restrict__ out, int K, int N, int SPLIT, int k0, int n0, int layer,
    int tid)
{
    const bool first = (n0 < SPLIT);
    const int scols = first ? SPLIT : (N - SPLIT);
    const float* S = (first ? A1 : A2) + (size_t)layer * K * scols
                     + (first ? n0 : (n0 - SPLIT));
    out += (size_t)layer * K * N;

    #pragma unroll
    for (int i = 0; i < 4; ++i) {
        const int c = tid + i * 256;
        const int kr = c >> 4, cc = c & 15;
        const float4 v = *(const float4*)(S + (size_t)(k0 + kr) * scols + cc * 4);
        T[kr][cc * 4 + 0] = v.x; T[kr][cc * 4 + 1] = v.y;
        T[kr][cc * 4 + 2] = v.z; T[kr][cc * 4 + 3] = v.w;
    }
    __syncthreads();
    #pragma unroll
    for (int i = 0; i < 4; ++i) {
        const int c = tid + i * 256;
        const int nr = c >> 4, cc = c & 15;
        ushort4 h;
        h.x = f2bf(T[cc * 4 + 0][nr]); h.y = f2bf(T[cc * 4 + 1][nr]);
        h.z = f2bf(T[cc * 4 + 2][nr]); h.w = f2bf(T[cc * 4 + 3][nr]);
        *(ushort4*)&out[(size_t)(n0 + nr) * K + k0 + cc * 4] = h;
    }
}

// ---------------------------------------------------------------------------
// prep: ALL one-time conversions in a single dispatch (jobs are independent).
//   blocks [0,256):    WcombT  = transpose+bf16 of [Wd|Wi]  (16 x 8 x 2)
//   blocks [256,384):  WoT     = transpose+bf16 of Wo        (4 x 16 x 2)
//   blocks [384,640):  Wsb     = bf16 copy of Ws (same layout), 524288 elems
//   blocks [640,2688): Xbf     = bf16 copy of X0, grid-stride
// ---------------------------------------------------------------------------
__global__ __launch_bounds__(256)
void prep(const float* __restrict__ Wd, const float* __restrict__ Wi,
          const float* __restrict__ Wo, const float* __restrict__ Ws,
          const float* __restrict__ X0,
          u16* __restrict__ WcombT, u16* __restrict__ WoT,
          u16* __restrict__ Wsb, u16* __restrict__ Xbf)
{
    __shared__ float T[64][65];
    const int bid = blockIdx.x;
    const int tid = threadIdx.x;

    if (bid < 256) {
        const int kx = bid & 15, ny = (bid >> 4) & 7, lz = bid >> 7;
        transpose_body(T, Wd, Wi, WcombT, 1024, 512, 256, kx * 64, ny * 64, lz, tid);
    } else if (bid < 384) {
        const int sub = bid - 256;
        const int kx = sub & 3, ny = (sub >> 2) & 15, lz = sub >> 6;
        transpose_body(T, Wo, Wo, WoT, 256, 1024, 1024, kx * 64, ny * 64, lz, tid);
    } else if (bid < 640) {
        // Wsb: 2*256*1024 = 524288 elems == 256 blocks * 256 thr * 8 exactly
        const size_t i = ((size_t)(bid - 384) * 256 + tid) * 8;
        const float4 a = *(const float4*)(Ws + i);
        const float4 b = *(const float4*)(Ws + i + 4);
        int4 o;
        o.x = (int)pk_bf2(a.x, a.y); o.y = (int)pk_bf2(a.z, a.w);
        o.z = (int)pk_bf2(b.x, b.y); o.w = (int)pk_bf2(b.z, b.w);
        *(int4*)(Wsb + i) = o;
    } else {
        const size_t total = (size_t)M_TOT * DIM;
        const size_t stride = (size_t)2048 * 256 * 8;
        for (size_t i = ((size_t)(bid - 640) * 256 + tid) * 8; i < total; i += stride) {
            const float4 a = *(const float4*)(X0 + i);
            const float4 b = *(const float4*)(X0 + i + 4);
            int4 o;
            o.x = (int)pk_bf2(a.x, a.y); o.y = (int)pk_bf2(a.z, a.w);
            o.z = (int)pk_bf2(b.x, b.y); o.w = (int)pk_bf2(b.z, b.w);
            *(int4*)(Xbf + i) = o;
        }
    }
}

#define BM 128
#define BN 128
#define BK 32

// ---------------------------------------------------------------------------
// gemm_bf16: C[M,N] = A[M,K] @ BT[N,K]^T, bf16 MFMA 16x16x32, m97 structure:
// 128x128 tile, linear LDS [128][32], width-16 global_load_lds staging.
// EPI: 0 none, 2 +bias+cs[row/64]. BF16OUT: write bf16. SWIZ: XCD swizzle.
// POOL: emit per-(batch,col) row-sums (each 128-row tile = 2 complete
// batches x 64 shots -> block-local, no atomics).
// ---------------------------------------------------------------------------
template<int EPI, bool SWIZ, bool BF16OUT, bool POOL>
__global__ __launch_bounds__(256)
void gemm_bf16(const u16* __restrict__ A, const u16* __restrict__ BT,
               void* __restrict__ Cv, const float* __restrict__ bo,
               const float* __restrict__ cs, float* __restrict__ pooled,
               int K, int ldc, int CB)
{
    __shared__ __align__(16) u16 As[BM * BK];   // 8 KiB
    __shared__ __align__(16) u16 Bs[BN * BK];   // 8 KiB

    const int tid = threadIdx.x;
    const int id  = blockIdx.x;
    int rb, cb;
    if (SWIZ) {
        const int xcd = id & 7, slot = id >> 3;
        rb = xcd + 8 * (slot / CB);
        cb = slot % CB;
    } else {
        rb = id / CB; cb = id % CB;
    }
    const int row0 = rb * BM, col0 = cb * BN;

    const int l  = tid & 63;
    const int w  = tid >> 6;
    const int wm = (w >> 1) * 64, wn = (w & 1) * 64;
    const int lr = l & 15, lq = l >> 4;

    // staging geometry: wave w covers row-groups {2w, 2w+1}, 16 rows each.
    // lane l -> row (l>>2) within group, bf16 col (l&3)*8 (16 B).
    // LDS dest = group*1024 B + l*16 B == linear row-major [128][32].
    const int sg   = w * 2;
    const int srow = l >> 2;
    const int scol = (l & 3) * 8;
    const u16* Ag = A  + (size_t)(row0 + sg * 16 + srow) * K + scol;
    const u16* Bg = BT + (size_t)(col0 + sg * 16 + srow) * K + scol;
    u16* Asd = &As[sg * 512 + l * 8];
    u16* Bsd = &Bs[sg * 512 + l * 8];

    f32x4 acc[4][4];
    #pragma unroll
    for (int i = 0; i < 4; ++i)
        #pragma unroll
        for (int j = 0; j < 4; ++j)
            acc[i][j] = (f32x4){0.f, 0.f, 0.f, 0.f};

    for (int k0 = 0; k0 < K; k0 += BK) {
        gld16(Ag + k0,                  Asd);
        gld16(Ag + (size_t)16 * K + k0, Asd + 512);
        gld16(Bg + k0,                  Bsd);
        gld16(Bg + (size_t)16 * K + k0, Bsd + 512);
        __syncthreads();

        bf16x8 af[4], bfr[4];
        #pragma unroll
        for (int i = 0; i < 4; ++i)
            af[i] = *(const bf16x8*)&As[(wm + i * 16 + lr) * BK + lq * 8];
        #pragma unroll
        for (int j = 0; j < 4; ++j)
            bfr[j] = *(const bf16x8*)&Bs[(wn + j * 16 + lr) * BK + lq * 8];

        #pragma unroll
        for (int i = 0; i < 4; ++i)
            #pragma unroll
            for (int j = 0; j < 4; ++j)
                acc[i][j] = __builtin_amdgcn_mfma_f32_16x16x32_bf16(
                    af[i], bfr[j], acc[i][j], 0, 0, 0);
        __syncthreads();
    }

    // epilogue: C/D layout col=lane&15, row=quad*4+reg
    float psum[4] = {0.f, 0.f, 0.f, 0.f};
    #pragma unroll
    for (int i = 0; i < 4; ++i) {
        const int grow = row0 + wm + i * 16 + lq * 4;
        #pragma unroll
        for (int j = 0; j < 4; ++j) {
            const int gcol = col0 + wn + j * 16 + lr;
            float addv = 0.f;
            if (EPI >= 1) addv += bo[gcol];
            if (EPI == 2) addv += cs[(size_t)(grow >> 6) * DIM + gcol];
            #pragma unroll
            for (int r = 0; r < 4; ++r) {
                const float val = acc[i][j][r] + addv;
                if (BF16OUT) ((u16*)Cv)[(size_t)(grow + r) * ldc + gcol] = f2bf(val);
                else         ((float*)Cv)[(size_t)(grow + r) * ldc + gcol] = val;
                if (POOL) psum[j] += val;
            }
        }
    }
    if (POOL) {
        // all 64 rows of this wave belong to one batch (wm fixed per wave)
        const int batch_w = (row0 + wm) >> 6;
        #pragma unroll
        for (int j = 0; j < 4; ++j) {
            float v = psum[j];
            v += __shfl_xor(v, 16, 64);   // reduce over lq (rows)
            v += __shfl_xor(v, 32, 64);
            if (lq == 0)
                pooled[(size_t)batch_w * DIM + col0 + wn + j * 16 + lr] = v;
        }
    }
}

// ---------------------------------------------------------------------------
// scan_cs: one block per batch, 1024 threads = 4 groups x 256 cols.
// Intra-block chunked scan (PQ read once, transcendentals once, no cross-
// block sync) -> hsb (bf16); final fp32 state kept in LDS; then all 1024
// threads compute cs[b,:] = state @ Ws + bs (Ws bf16, L2-resident).
// ---------------------------------------------------------------------------
__global__ __launch_bounds__(1024)
void scan_cs(const float* __restrict__ PQ,
             const float* __restrict__ bd, const float* __restrict__ bi,
             const float* __restrict__ A_log,
             const u16* __restrict__ Wsb, const float* __restrict__ bs,
             u16* __restrict__ hsb, float* __restrict__ csbuf)
{
    const int b = blockIdx.x;
    const int n = threadIdx.x & 255;
    const int g = threadIdx.x >> 8;                // 0..3
    const float bdv = bd[n], biv = bi[n];
    const float spA = softplus_f(A_log[n]);
    const size_t m0 = (size_t)b * SHOTS + g * GSTEP;
    const float* base = PQ + m0 * 512 + n;

    // load the group's P,Q (32 independent coalesced loads)
    float dec[GSTEP], drv[GSTEP];
    #pragma unroll
    for (int s = 0; s < GSTEP; ++s) {
        dec[s] = base[s * 512];          // P
        drv[s] = base[s * 512 + SDIM];   // Q
    }
    // transform once: dec/drv + local summary (a = prod dec, hl = local scan)
    float a = 1.f, hl = 0.f;
    #pragma unroll
    for (int s = 0; s < GSTEP; ++s) {
        const float delta = softplus_f(dec[s] + bdv);
        const float d  = __expf(-delta * spA);
        const float gv = delta * (drv[s] + biv);
        dec[s] = d; drv[s] = gv;
        a *= d; hl = d * hl + gv;
    }

    __shared__ float2 grp[SGRP][SDIM];
    __shared__ float st[SDIM];
    grp[g][n] = make_float2(a, hl);
    __syncthreads();

    // prefix over earlier groups (uniform-per-wave trip count)
    float h = 0.f;
    for (int j = 0; j < g; ++j) {
        const float2 sv = grp[j][n];
        h = sv.x * h + sv.y;
    }

    // replay from registers
    u16* hout = hsb + m0 * SDIM + n;
    #pragma unroll
    for (int s = 0; s < GSTEP; ++s) {
        h = dec[s] * h + drv[s];
        hout[s * SDIM] = f2bf(h);
    }
    if (g == SGRP - 1) st[n] = h;   // fp32 state
    __syncthreads();

    // cs matvec: thread d owns one output column
    const int d = threadIdx.x;
    float c = bs[d];
    const u16* wp = Wsb + d;
    #pragma unroll 8
    for (int k = 0; k < SDIM; ++k)
        c += st[k] * bf2f(wp[(size_t)k * DIM]);
    csbuf[(size_t)b * DIM + d] = c;
}

// ---------------------------------------------------------------------------
// final_kernel: pooled(sum) -> mean, + class_state, LayerNorm. ~2 MB traffic.
// ---------------------------------------------------------------------------
__global__ __launch_bounds__(1024)
void final_kernel(const float* __restrict__ pooled, const float* __restrict__ cs,
                  const float* __restrict__ gamma, const float* __restrict__ beta,
                  float* __restrict__ out)
{
    const int b = blockIdx.x;
    const int d = threadIdx.x;

    const float p = cs[(size_t)b * DIM + d]
                  + pooled[(size_t)b * DIM + d] * (1.f / SHOTS);

    __shared__ float rsum[1024], rsq[1024];
    rsum[d] = p; rsq[d] = p * p;
    __syncthreads();
    for (int off = 512; off > 0; off >>= 1) {
        if (d < off) { rsum[d] += rsum[d + off]; rsq[d] += rsq[d + off]; }
        __syncthreads();
    }
    const float mu  = rsum[0] * (1.f / DIM);
    const float var = rsq[0] * (1.f / DIM) - mu * mu;
    const float inv = rsqrtf(var + 1e-5f);

    out[(size_t)b * DIM + d] = (p - mu) * inv * gamma[d] + beta[d];
}

// ---------------------------------------------------------------------------

extern "C" void kernel_launch(void* const* d_in, const int* in_sizes, int n_in,
                              void* d_out, int out_size, void* d_ws, size_t ws_size,
                              hipStream_t stream)
{
    const float* X0    = (const float*)d_in[0];
    const float* Wd    = (const float*)d_in[1];
    const float* bd    = (const float*)d_in[2];
    const float* Wi    = (const float*)d_in[3];
    const float* bi    = (const float*)d_in[4];
    const float* A_log = (const float*)d_in[5];
    const float* Wo    = (const float*)d_in[6];
    const float* bo    = (const float*)d_in[7];
    const float* Ws    = (const float*)d_in[8];
    const float* bs    = (const float*)d_in[9];
    const float* gamma = (const float*)d_in[10];
    const float* beta  = (const float*)d_in[11];

    float* out_cr     = (float*)d_out;                  // [BATCH, DIM]
    float* out_hidden = out_cr + (size_t)BATCH * DIM;   // [BATCH, SHOTS, DIM] fp32

    // Xbf (bf16 activations) lives in the out_hidden region as scratch; it is
    // dead before the layer-1 hidden GEMM performs the fp32 out_hidden write.
    u16* Xbf = (u16*)out_hidden;

    // ws layout: ~48.2 MB <= proven 51.6 MB footprint
    char* w = (char*)d_ws;
    float*  PQ     = (float*)w;  w += (size_t)M_TOT * 512 * 4;          // 33.55 MB
    float*  csbuf  = (float*)w;  w += (size_t)BATCH * DIM * 4;          //  1.05 MB
    float*  pooled = (float*)w;  w += (size_t)BATCH * DIM * 4;          //  1.05 MB
    u16*    hsb    = (u16*)w;    w += (size_t)M_TOT * SDIM * 2;         //  8.39 MB
    u16*    WcombT = (u16*)w;    w += (size_t)DEPTH * 512 * 1024 * 2;   //  2.10 MB
    u16*    WoT    = (u16*)w;    w += (size_t)DEPTH * 1024 * 256 * 2;   //  1.05 MB
    u16*    Wsb    = (u16*)w;    w += (size_t)DEPTH * SDIM * DIM * 2;   //  1.05 MB

    // all one-time conversions in ONE dispatch
    prep<<<2688, 256, 0, stream>>>(Wd, Wi, Wo, Ws, X0, WcombT, WoT, Wsb, Xbf);

    for (int l = 0; l < DEPTH; ++l) {
        // PQ = Xbf @ [Wd|Wi]  (M=16384, N=512, K=1024)
        gemm_bf16<0, true, false, false><<<512, 256, 0, stream>>>(
            Xbf, WcombT + (size_t)l * 512 * 1024, PQ, nullptr, nullptr, nullptr,
            1024, 512, 4);
        // fused intra-block scan + class_state matvec
        scan_cs<<<BATCH, 1024, 0, stream>>>(
            PQ, bd + l * SDIM, bi + l * SDIM, A_log + l * SDIM,
            Wsb + (size_t)l * SDIM * DIM, bs + l * DIM, hsb, csbuf);
        // hidden = hs @ Wo + bo + class_state  (M=16384, N=1024, K=256)
        if (l < DEPTH - 1) {
            gemm_bf16<2, true, true, false><<<1024, 256, 0, stream>>>(
                hsb, WoT + (size_t)l * 1024 * 256, Xbf, bo + l * DIM, csbuf,
                nullptr, 256, 1024, 8);
        } else {
            gemm_bf16<2, true, false, true><<<1024, 256, 0, stream>>>(
                hsb, WoT + (size_t)l * 1024 * 256, out_hidden, bo + l * DIM, csbuf,
                pooled, 256, 1024, 8);
        }
    }
    final_kernel<<<BATCH, 1024, 0, stream>>>(pooled, csbuf, gamma, beta, out_cr);
}

// Round 6
// 272.301 us; speedup vs baseline: 3.8573x; 1.0887x over previous
//
#include <hip/hip_runtime.h>
#include <hip/hip_bf16.h>

#define DEPTH 2
#define DIM   1024
#define SDIM  256
#define BATCH 256
#define SHOTS 64
#define M_TOT (BATCH*SHOTS)   // 16384
#define SGRP  4               // scan groups per batch
#define GSTEP (SHOTS/SGRP)    // 16 steps per group

typedef __attribute__((ext_vector_type(8))) short bf16x8;  // 8 bf16 = 4 VGPRs
typedef __attribute__((ext_vector_type(4))) float f32x4;
typedef unsigned short u16;

__device__ __forceinline__ u16 f2bf(float f) {
    union { float f; unsigned u; } v; v.f = f;
    unsigned r = v.u + 0x7fffu + ((v.u >> 16) & 1u);
    return (u16)(r >> 16);
}

__device__ __forceinline__ unsigned pk_bf2(float a, float b) {
    union { __hip_bfloat162 h2; unsigned u; } c;
    c.h2 = __float22bfloat162_rn(make_float2(a, b));   // v_cvt_pk_bf16_f32
    return c.u;
}

__device__ __forceinline__ float bf2f(u16 h) {
    union { unsigned u; float f; } c; c.u = (unsigned)h << 16; return c.f;
}

// fast softplus: 2 HW transcendentals (v_exp_f32 + v_log_f32), no libm.
// |err| <= ~3e-7 vs log1pf path -- far below bf16 rounding noise.
__device__ __forceinline__ float softplus_f(float x) {
    if (x > 15.f) return x;
    return __logf(1.f + __expf(x));
}

// async global->LDS, 16B per lane (global_load_lds_dwordx4)
__device__ __forceinline__ void gld16(const u16* g, u16* l) {
    __builtin_amdgcn_global_load_lds(
        (const __attribute__((address_space(1))) unsigned int*)g,
        (__attribute__((address_space(3))) unsigned int*)l, 16, 0, 0);
}

// ---------------------------------------------------------------------------
// transpose body: out[n][k] (bf16) = in[k][n] (fp32), 64x64 tile via LDS.
// ---------------------------------------------------------------------------
__device__ __forceinline__ void transpose_body(
    float T[64][65], const float* __restrict__ A1, const float* __restrict__ A2,
    u16* __restrict__ out, int K, int N, int SPLIT, int k0, int n0, int layer,
    int tid)
{
    const bool first = (n0 < SPLIT);
    const int scols = first ? SPLIT : (N - SPLIT);
    const float* S = (first ? A1 : A2) + (size_t)layer * K * scols
                     + (first ? n0 : (n0 - SPLIT));
    out += (size_t)layer * K * N;

    #pragma unroll
    for (int i = 0; i < 4; ++i) {
        const int c = tid + i * 256;
        const int kr = c >> 4, cc = c & 15;
        const float4 v = *(const float4*)(S + (size_t)(k0 + kr) * scols + cc * 4);
        T[kr][cc * 4 + 0] = v.x; T[kr][cc * 4 + 1] = v.y;
        T[kr][cc * 4 + 2] = v.z; T[kr][cc * 4 + 3] = v.w;
    }
    __syncthreads();
    #pragma unroll
    for (int i = 0; i < 4; ++i) {
        const int c = tid + i * 256;
        const int nr = c >> 4, cc = c & 15;
        ushort4 h;
        h.x = f2bf(T[cc * 4 + 0][nr]); h.y = f2bf(T[cc * 4 + 1][nr]);
        h.z = f2bf(T[cc * 4 + 2][nr]); h.w = f2bf(T[cc * 4 + 3][nr]);
        *(ushort4*)&out[(size_t)(n0 + nr) * K + k0 + cc * 4] = h;
    }
}

// ---------------------------------------------------------------------------
// prep: ALL one-time conversions in a single dispatch (jobs are independent).
//   blocks [0,256):    WcombT  = transpose+bf16 of [Wd|Wi]  (16 x 8 x 2)
//   blocks [256,384):  WoT     = transpose+bf16 of Wo        (4 x 16 x 2)
//   blocks [384,640):  Wsb     = bf16 copy of Ws (same layout), 524288 elems
//   blocks [640,2688): Xbf     = bf16 copy of X0, grid-stride
// ---------------------------------------------------------------------------
__global__ __launch_bounds__(256)
void prep(const float* __restrict__ Wd, const float* __restrict__ Wi,
          const float* __restrict__ Wo, const float* __restrict__ Ws,
          const float* __restrict__ X0,
          u16* __restrict__ WcombT, u16* __restrict__ WoT,
          u16* __restrict__ Wsb, u16* __restrict__ Xbf)
{
    __shared__ float T[64][65];
    const int bid = blockIdx.x;
    const int tid = threadIdx.x;

    if (bid < 256) {
        const int kx = bid & 15, ny = (bid >> 4) & 7, lz = bid >> 7;
        transpose_body(T, Wd, Wi, WcombT, 1024, 512, 256, kx * 64, ny * 64, lz, tid);
    } else if (bid < 384) {
        const int sub = bid - 256;
        const int kx = sub & 3, ny = (sub >> 2) & 15, lz = sub >> 6;
        transpose_body(T, Wo, Wo, WoT, 256, 1024, 1024, kx * 64, ny * 64, lz, tid);
    } else if (bid < 640) {
        // Wsb: 2*256*1024 = 524288 elems == 256 blocks * 256 thr * 8 exactly
        const size_t i = ((size_t)(bid - 384) * 256 + tid) * 8;
        const float4 a = *(const float4*)(Ws + i);
        const float4 b = *(const float4*)(Ws + i + 4);
        int4 o;
        o.x = (int)pk_bf2(a.x, a.y); o.y = (int)pk_bf2(a.z, a.w);
        o.z = (int)pk_bf2(b.x, b.y); o.w = (int)pk_bf2(b.z, b.w);
        *(int4*)(Wsb + i) = o;
    } else {
        const size_t total = (size_t)M_TOT * DIM;
        const size_t stride = (size_t)2048 * 256 * 8;
        for (size_t i = ((size_t)(bid - 640) * 256 + tid) * 8; i < total; i += stride) {
            const float4 a = *(const float4*)(X0 + i);
            const float4 b = *(const float4*)(X0 + i + 4);
            int4 o;
            o.x = (int)pk_bf2(a.x, a.y); o.y = (int)pk_bf2(a.z, a.w);
            o.z = (int)pk_bf2(b.x, b.y); o.w = (int)pk_bf2(b.z, b.w);
            *(int4*)(Xbf + i) = o;
        }
    }
}

#define BM 128
#define BN 128
#define BK 32

// ---------------------------------------------------------------------------
// gemm_bf16: C[M,N] = A[M,K] @ BT[N,K]^T, bf16 MFMA 16x16x32, m97 structure:
// 128x128 tile, linear LDS [128][32], width-16 global_load_lds staging.
// EPI: 0 none, 2 +bias+cs[row/64]. BF16OUT: write bf16. SWIZ: XCD swizzle.
// POOL: emit per-(batch,col) row-sums (each 128-row tile = 2 complete
// batches x 64 shots -> block-local, no atomics).
// ---------------------------------------------------------------------------
template<int EPI, bool SWIZ, bool BF16OUT, bool POOL>
__global__ __launch_bounds__(256)
void gemm_bf16(const u16* __restrict__ A, const u16* __restrict__ BT,
               void* __restrict__ Cv, const float* __restrict__ bo,
               const float* __restrict__ cs, float* __restrict__ pooled,
               int K, int ldc, int CB)
{
    __shared__ __align__(16) u16 As[BM * BK];   // 8 KiB
    __shared__ __align__(16) u16 Bs[BN * BK];   // 8 KiB

    const int tid = threadIdx.x;
    const int id  = blockIdx.x;
    int rb, cb;
    if (SWIZ) {
        const int xcd = id & 7, slot = id >> 3;
        rb = xcd + 8 * (slot / CB);
        cb = slot % CB;
    } else {
        rb = id / CB; cb = id % CB;
    }
    const int row0 = rb * BM, col0 = cb * BN;

    const int l  = tid & 63;
    const int w  = tid >> 6;
    const int wm = (w >> 1) * 64, wn = (w & 1) * 64;
    const int lr = l & 15, lq = l >> 4;

    // staging geometry: wave w covers row-groups {2w, 2w+1}, 16 rows each.
    // lane l -> row (l>>2) within group, bf16 col (l&3)*8 (16 B).
    // LDS dest = group*1024 B + l*16 B == linear row-major [128][32].
    const int sg   = w * 2;
    const int srow = l >> 2;
    const int scol = (l & 3) * 8;
    const u16* Ag = A  + (size_t)(row0 + sg * 16 + srow) * K + scol;
    const u16* Bg = BT + (size_t)(col0 + sg * 16 + srow) * K + scol;
    u16* Asd = &As[sg * 512 + l * 8];
    u16* Bsd = &Bs[sg * 512 + l * 8];

    f32x4 acc[4][4];
    #pragma unroll
    for (int i = 0; i < 4; ++i)
        #pragma unroll
        for (int j = 0; j < 4; ++j)
            acc[i][j] = (f32x4){0.f, 0.f, 0.f, 0.f};

    for (int k0 = 0; k0 < K; k0 += BK) {
        gld16(Ag + k0,                  Asd);
        gld16(Ag + (size_t)16 * K + k0, Asd + 512);
        gld16(Bg + k0,                  Bsd);
        gld16(Bg + (size_t)16 * K + k0, Bsd + 512);
        __syncthreads();

        bf16x8 af[4], bfr[4];
        #pragma unroll
        for (int i = 0; i < 4; ++i)
            af[i] = *(const bf16x8*)&As[(wm + i * 16 + lr) * BK + lq * 8];
        #pragma unroll
        for (int j = 0; j < 4; ++j)
            bfr[j] = *(const bf16x8*)&Bs[(wn + j * 16 + lr) * BK + lq * 8];

        #pragma unroll
        for (int i = 0; i < 4; ++i)
            #pragma unroll
            for (int j = 0; j < 4; ++j)
                acc[i][j] = __builtin_amdgcn_mfma_f32_16x16x32_bf16(
                    af[i], bfr[j], acc[i][j], 0, 0, 0);
        __syncthreads();
    }

    // epilogue: C/D layout col=lane&15, row=quad*4+reg
    float psum[4] = {0.f, 0.f, 0.f, 0.f};
    #pragma unroll
    for (int i = 0; i < 4; ++i) {
        const int grow = row0 + wm + i * 16 + lq * 4;
        #pragma unroll
        for (int j = 0; j < 4; ++j) {
            const int gcol = col0 + wn + j * 16 + lr;
            float addv = 0.f;
            if (EPI >= 1) addv += bo[gcol];
            if (EPI == 2) addv += cs[(size_t)(grow >> 6) * DIM + gcol];
            #pragma unroll
            for (int r = 0; r < 4; ++r) {
                const float val = acc[i][j][r] + addv;
                if (BF16OUT) ((u16*)Cv)[(size_t)(grow + r) * ldc + gcol] = f2bf(val);
                else         ((float*)Cv)[(size_t)(grow + r) * ldc + gcol] = val;
                if (POOL) psum[j] += val;
            }
        }
    }
    if (POOL) {
        // all 64 rows of this wave belong to one batch (wm fixed per wave)
        const int batch_w = (row0 + wm) >> 6;
        #pragma unroll
        for (int j = 0; j < 4; ++j) {
            float v = psum[j];
            v += __shfl_xor(v, 16, 64);   // reduce over lq (rows)
            v += __shfl_xor(v, 32, 64);
            if (lq == 0)
                pooled[(size_t)batch_w * DIM + col0 + wn + j * 16 + lr] = v;
        }
    }
}

// ---------------------------------------------------------------------------
// scan_cs: one block per batch, 1024 threads = 4 groups x 256 cols.
// dec/drv staged in LDS [s][tid] (lane-consecutive -> conflict-free) so
// NOTHING spills to scratch (round-5 bug: VGPR_Count=28 < the 32 floats of
// per-thread arrays => scratch). Transcendentals computed ONCE. Then the
// fp32 state stays in LDS and cs = state @ Ws + bs is computed with a
// 4-way k-split and ushort4 vector loads.
// ---------------------------------------------------------------------------
__global__ __launch_bounds__(1024)
void scan_cs(const float* __restrict__ PQ,
             const float* __restrict__ bd, const float* __restrict__ bi,
             const float* __restrict__ A_log,
             const u16* __restrict__ Wsb, const float* __restrict__ bs,
             u16* __restrict__ hsb, float* __restrict__ csbuf)
{
    __shared__ __align__(16) float decS[GSTEP][1024];  // 64 KB (reused: psum)
    __shared__ float drvS[GSTEP][1024];                // 64 KB
    __shared__ float2 grp[SGRP][SDIM];                 //  8 KB
    __shared__ float st[SDIM];                         //  1 KB

    const int tid = threadIdx.x;
    const int b = blockIdx.x;
    const int n = tid & 255;
    const int g = tid >> 8;                // 0..3
    const float bdv = bd[n], biv = bi[n];
    const float spA = softplus_f(A_log[n]);
    const size_t m0 = (size_t)b * SHOTS + g * GSTEP;
    const float* base = PQ + m0 * 512 + n;

    // transform once: dec/drv -> LDS, local summary (a = prod dec, hl)
    float a = 1.f, hl = 0.f;
    #pragma unroll
    for (int s = 0; s < GSTEP; ++s) {
        const float p = base[s * 512];            // P
        const float q = base[s * 512 + SDIM];     // Q
        const float delta = softplus_f(p + bdv);
        const float d  = __expf(-delta * spA);
        const float gv = delta * (q + biv);
        decS[s][tid] = d; drvS[s][tid] = gv;
        a *= d; hl = d * hl + gv;
    }

    grp[g][n] = make_float2(a, hl);
    __syncthreads();

    // prefix over earlier groups (uniform-per-wave trip count)
    float h = 0.f;
    for (int j = 0; j < g; ++j) {
        const float2 sv = grp[j][n];
        h = sv.x * h + sv.y;
    }

    // replay from LDS
    u16* hout = hsb + m0 * SDIM + n;
    #pragma unroll
    for (int s = 0; s < GSTEP; ++s) {
        h = decS[s][tid] * h + drvS[s][tid];
        hout[s * SDIM] = f2bf(h);
    }
    if (g == SGRP - 1) st[n] = h;   // fp32 state
    __syncthreads();                // also: all decS reads done (psum reuse)

    // cs matvec, 4-way k-split: quarter q = g, col group c = n.
    // thread accumulates f32x4 over 64 k's with ushort4 loads (coalesced).
    const int dbase = n * 4;
    f32x4 part = {0.f, 0.f, 0.f, 0.f};
    const int kq = g * 64;
    #pragma unroll 8
    for (int k = 0; k < 64; ++k) {
        const float sk = st[kq + k];                         // LDS broadcast
        const ushort4 wv = *(const ushort4*)&Wsb[(size_t)(kq + k) * DIM + dbase];
        part[0] += sk * bf2f(wv.x); part[1] += sk * bf2f(wv.y);
        part[2] += sk * bf2f(wv.z); part[3] += sk * bf2f(wv.w);
    }
    f32x4* psum = (f32x4*)decS;     // reuse 16 KB of decS
    psum[g * 256 + n] = part;
    __syncthreads();
    if (tid < 256) {
        const f32x4 s0 = psum[tid], s1 = psum[256 + tid];
        const f32x4 s2 = psum[512 + tid], s3 = psum[768 + tid];
        const float4 bv = *(const float4*)(bs + tid * 4);
        float4 o;
        o.x = bv.x + s0[0] + s1[0] + s2[0] + s3[0];
        o.y = bv.y + s0[1] + s1[1] + s2[1] + s3[1];
        o.z = bv.z + s0[2] + s1[2] + s2[2] + s3[2];
        o.w = bv.w + s0[3] + s1[3] + s2[3] + s3[3];
        *(float4*)(csbuf + (size_t)b * DIM + tid * 4) = o;
    }
}

// ---------------------------------------------------------------------------
// final_kernel: pooled(sum) -> mean, + class_state, LayerNorm. ~2 MB traffic.
// ---------------------------------------------------------------------------
__global__ __launch_bounds__(1024)
void final_kernel(const float* __restrict__ pooled, const float* __restrict__ cs,
                  const float* __restrict__ gamma, const float* __restrict__ beta,
                  float* __restrict__ out)
{
    const int b = blockIdx.x;
    const int d = threadIdx.x;

    const float p = cs[(size_t)b * DIM + d]
                  + pooled[(size_t)b * DIM + d] * (1.f / SHOTS);

    __shared__ float rsum[1024], rsq[1024];
    rsum[d] = p; rsq[d] = p * p;
    __syncthreads();
    for (int off = 512; off > 0; off >>= 1) {
        if (d < off) { rsum[d] += rsum[d + off]; rsq[d] += rsq[d + off]; }
        __syncthreads();
    }
    const float mu  = rsum[0] * (1.f / DIM);
    const float var = rsq[0] * (1.f / DIM) - mu * mu;
    const float inv = rsqrtf(var + 1e-5f);

    out[(size_t)b * DIM + d] = (p - mu) * inv * gamma[d] + beta[d];
}

// ---------------------------------------------------------------------------

extern "C" void kernel_launch(void* const* d_in, const int* in_sizes, int n_in,
                              void* d_out, int out_size, void* d_ws, size_t ws_size,
                              hipStream_t stream)
{
    const float* X0    = (const float*)d_in[0];
    const float* Wd    = (const float*)d_in[1];
    const float* bd    = (const float*)d_in[2];
    const float* Wi    = (const float*)d_in[3];
    const float* bi    = (const float*)d_in[4];
    const float* A_log = (const float*)d_in[5];
    const float* Wo    = (const float*)d_in[6];
    const float* bo    = (const float*)d_in[7];
    const float* Ws    = (const float*)d_in[8];
    const float* bs    = (const float*)d_in[9];
    const float* gamma = (const float*)d_in[10];
    const float* beta  = (const float*)d_in[11];

    float* out_cr     = (float*)d_out;                  // [BATCH, DIM]
    float* out_hidden = out_cr + (size_t)BATCH * DIM;   // [BATCH, SHOTS, DIM] fp32

    // Xbf (bf16 activations) lives in the out_hidden region as scratch; it is
    // dead before the layer-1 hidden GEMM performs the fp32 out_hidden write.
    u16* Xbf = (u16*)out_hidden;

    // ws layout: ~48.2 MB <= proven 51.6 MB footprint
    char* w = (char*)d_ws;
    float*  PQ     = (float*)w;  w += (size_t)M_TOT * 512 * 4;          // 33.55 MB
    float*  csbuf  = (float*)w;  w += (size_t)BATCH * DIM * 4;          //  1.05 MB
    float*  pooled = (float*)w;  w += (size_t)BATCH * DIM * 4;          //  1.05 MB
    u16*    hsb    = (u16*)w;    w += (size_t)M_TOT * SDIM * 2;         //  8.39 MB
    u16*    WcombT = (u16*)w;    w += (size_t)DEPTH * 512 * 1024 * 2;   //  2.10 MB
    u16*    WoT    = (u16*)w;    w += (size_t)DEPTH * 1024 * 256 * 2;   //  1.05 MB
    u16*    Wsb    = (u16*)w;    w += (size_t)DEPTH * SDIM * DIM * 2;   //  1.05 MB

    // all one-time conversions in ONE dispatch
    prep<<<2688, 256, 0, stream>>>(Wd, Wi, Wo, Ws, X0, WcombT, WoT, Wsb, Xbf);

    for (int l = 0; l < DEPTH; ++l) {
        // PQ = Xbf @ [Wd|Wi]  (M=16384, N=512, K=1024)
        gemm_bf16<0, true, false, false><<<512, 256, 0, stream>>>(
            Xbf, WcombT + (size_t)l * 512 * 1024, PQ, nullptr, nullptr, nullptr,
            1024, 512, 4);
        // fused intra-block scan + class_state matvec (LDS-staged dec/drv)
        scan_cs<<<BATCH, 1024, 0, stream>>>(
            PQ, bd + l * SDIM, bi + l * SDIM, A_log + l * SDIM,
            Wsb + (size_t)l * SDIM * DIM, bs + l * DIM, hsb, csbuf);
        // hidden = hs @ Wo + bo + class_state  (M=16384, N=1024, K=256)
        if (l < DEPTH - 1) {
            gemm_bf16<2, true, true, false><<<1024, 256, 0, stream>>>(
                hsb, WoT + (size_t)l * 1024 * 256, Xbf, bo + l * DIM, csbuf,
                nullptr, 256, 1024, 8);
        } else {
            gemm_bf16<2, true, false, true><<<1024, 256, 0, stream>>>(
                hsb, WoT + (size_t)l * 1024 * 256, out_hidden, bo + l * DIM, csbuf,
                pooled, 256, 1024, 8);
        }
    }
    final_kernel<<<BATCH, 1024, 0, stream>>>(pooled, csbuf, gamma, beta, out_cr);
}

// Round 8
// 252.419 us; speedup vs baseline: 4.1611x; 1.0788x over previous
//
#include <hip/hip_runtime.h>
#include <hip/hip_bf16.h>

#define DEPTH 2
#define DIM   1024
#define SDIM  256
#define BATCH 256
#define SHOTS 64
#define M_TOT (BATCH*SHOTS)   // 16384

typedef __attribute__((ext_vector_type(8))) short bf16x8;  // 8 bf16 = 4 VGPRs
typedef __attribute__((ext_vector_type(4))) float f32x4;
typedef unsigned short u16;

__device__ __forceinline__ u16 f2bf(float f) {
    union { float f; unsigned u; } v; v.f = f;
    unsigned r = v.u + 0x7fffu + ((v.u >> 16) & 1u);
    return (u16)(r >> 16);
}

__device__ __forceinline__ unsigned pk_bf2(float a, float b) {
    union { __hip_bfloat162 h2; unsigned u; } c;
    c.h2 = __float22bfloat162_rn(make_float2(a, b));   // v_cvt_pk_bf16_f32
    return c.u;
}

__device__ __forceinline__ float bf2f(u16 h) {
    union { unsigned u; float f; } c; c.u = (unsigned)h << 16; return c.f;
}

// fast softplus: 2 HW transcendentals (v_exp_f32 + v_log_f32), no libm.
__device__ __forceinline__ float softplus_f(float x) {
    if (x > 15.f) return x;
    return __logf(1.f + __expf(x));
}

// async global->LDS, 16B per lane (global_load_lds_dwordx4)
__device__ __forceinline__ void gld16(const u16* g, u16* l) {
    __builtin_amdgcn_global_load_lds(
        (const __attribute__((address_space(1))) unsigned int*)g,
        (__attribute__((address_space(3))) unsigned int*)l, 16, 0, 0);
}

// ---------------------------------------------------------------------------
// transpose body: out[destbase+nr][k] (bf16) = in[k][n0+nr] (fp32).
// destbase lets prep permute output rows (P|Q block layout for WcombT).
// ---------------------------------------------------------------------------
__device__ __forceinline__ void transpose_body(
    float T[64][65], const float* __restrict__ A1, const float* __restrict__ A2,
    u16* __restrict__ out, int K, int SPLIT, int k0, int n0, int destbase,
    int layer, int N, int tid)
{
    const bool first = (n0 < SPLIT);
    const int scols = first ? SPLIT : (N - SPLIT);
    const float* S = (first ? A1 : A2) + (size_t)layer * K * scols
                     + (first ? n0 : (n0 - SPLIT));
    out += (size_t)layer * K * N;

    #pragma unroll
    for (int i = 0; i < 4; ++i) {
        const int c = tid + i * 256;
        const int kr = c >> 4, cc = c & 15;
        const float4 v = *(const float4*)(S + (size_t)(k0 + kr) * scols + cc * 4);
        T[kr][cc * 4 + 0] = v.x; T[kr][cc * 4 + 1] = v.y;
        T[kr][cc * 4 + 2] = v.z; T[kr][cc * 4 + 3] = v.w;
    }
    __syncthreads();
    #pragma unroll
    for (int i = 0; i < 4; ++i) {
        const int c = tid + i * 256;
        const int nr = c >> 4, cc = c & 15;
        ushort4 h;
        h.x = f2bf(T[cc * 4 + 0][nr]); h.y = f2bf(T[cc * 4 + 1][nr]);
        h.z = f2bf(T[cc * 4 + 2][nr]); h.w = f2bf(T[cc * 4 + 3][nr]);
        *(ushort4*)&out[(size_t)(destbase + nr) * K + k0 + cc * 4] = h;
    }
}

// ---------------------------------------------------------------------------
// prep: ALL one-time conversions in a single dispatch.
//   blocks [0,256):    WcombT (P|Q block layout: rows [cb*128,+64)=Wd cols
//                      cb*64.., rows [cb*128+64,+64)=Wi cols cb*64..)
//   blocks [256,384):  WoT = transpose+bf16 of Wo
//   blocks [384,640):  Wsb = bf16 copy of Ws (original layout)
//   blocks [640,2688): Xbf = bf16 copy of X0
// ---------------------------------------------------------------------------
__global__ __launch_bounds__(256)
void prep(const float* __restrict__ Wd, const float* __restrict__ Wi,
          const float* __restrict__ Wo, const float* __restrict__ Ws,
          const float* __restrict__ X0,
          u16* __restrict__ WcombT, u16* __restrict__ WoT,
          u16* __restrict__ Wsb, u16* __restrict__ Xbf)
{
    __shared__ float T[64][65];
    const int bid = blockIdx.x;
    const int tid = threadIdx.x;

    if (bid < 256) {
        const int kx = bid & 15, ny = (bid >> 4) & 7, lz = bid >> 7;
        const int n0 = ny * 64;
        // P|Q block layout: Wd col n -> row (n>>6)*128 + (n&63);
        //                   Wi col n -> row (n>>6)*128 + 64 + (n&63)
        const int destbase = (n0 < 256) ? (n0 >> 6) * 128
                                        : ((n0 - 256) >> 6) * 128 + 64;
        transpose_body(T, Wd, Wi, WcombT, 1024, 256, kx * 64, n0, destbase,
                       lz, 512, tid);
    } else if (bid < 384) {
        const int sub = bid - 256;
        const int kx = sub & 3, ny = (sub >> 2) & 15, lz = sub >> 6;
        transpose_body(T, Wo, Wo, WoT, 256, 1024, kx * 64, ny * 64, ny * 64,
                       lz, 1024, tid);
    } else if (bid < 640) {
        const size_t i = ((size_t)(bid - 384) * 256 + tid) * 8;
        const float4 a = *(const float4*)(Ws + i);
        const float4 b = *(const float4*)(Ws + i + 4);
        int4 o;
        o.x = (int)pk_bf2(a.x, a.y); o.y = (int)pk_bf2(a.z, a.w);
        o.z = (int)pk_bf2(b.x, b.y); o.w = (int)pk_bf2(b.z, b.w);
        *(int4*)(Wsb + i) = o;
    } else {
        const size_t total = (size_t)M_TOT * DIM;
        const size_t stride = (size_t)2048 * 256 * 8;
        for (size_t i = ((size_t)(bid - 640) * 256 + tid) * 8; i < total; i += stride) {
            const float4 a = *(const float4*)(X0 + i);
            const float4 b = *(const float4*)(X0 + i + 4);
            int4 o;
            o.x = (int)pk_bf2(a.x, a.y); o.y = (int)pk_bf2(a.z, a.w);
            o.z = (int)pk_bf2(b.x, b.y); o.w = (int)pk_bf2(b.z, b.w);
            *(int4*)(Xbf + i) = o;
        }
    }
}

#define BM 128
#define BN 128
#define BK 32

// staging geometry shared by both GEMMs (proven m97 structure):
// wave w covers row-groups {2w,2w+1}, lane l -> row l>>2, col (l&3)*8.

// ---------------------------------------------------------------------------
// gemm_pq_scan: PQ = Xbf @ WcombT^T with the selective scan FUSED into the
// epilogue. Tile 128x128 = 2 batches x (P|Q for 64 states). Per batch:
// acc -> LDS Ct[64][129] fp32, 4-segment scan (threads = 4 seg x 64 cols,
// lane-consecutive -> conflict-free), hs -> global bf16, state -> fp32.
// PQ never touches global memory.
// ---------------------------------------------------------------------------
__global__ __launch_bounds__(256)
void gemm_pq_scan(const u16* __restrict__ A, const u16* __restrict__ BT,
                  const float* __restrict__ bd, const float* __restrict__ bi,
                  const float* __restrict__ A_log,
                  u16* __restrict__ hsb, float* __restrict__ stateb, int CB)
{
    __shared__ __align__(16) u16 As[BM * BK];   // 8 KiB
    __shared__ __align__(16) u16 Bs[BN * BK];   // 8 KiB
    __shared__ float Ct[64][129];               // 33 KiB
    __shared__ float2 grp[4][64];               //  2 KiB

    const int tid = threadIdx.x;
    const int id  = blockIdx.x;
    const int xcd = id & 7, slot = id >> 3;
    const int rb = xcd + 8 * (slot / CB);
    const int cb = slot % CB;
    const int row0 = rb * BM, col0 = cb * BN;
    const int K = 1024;

    const int l  = tid & 63;
    const int w  = tid >> 6;
    const int wm = (w >> 1) * 64, wn = (w & 1) * 64;
    const int lr = l & 15, lq = l >> 4;

    const int sg   = w * 2;
    const int srow = l >> 2;
    const int scol = (l & 3) * 8;
    const u16* Ag = A  + (size_t)(row0 + sg * 16 + srow) * K + scol;
    const u16* Bg = BT + (size_t)(col0 + sg * 16 + srow) * K + scol;
    u16* Asd = &As[sg * 512 + l * 8];
    u16* Bsd = &Bs[sg * 512 + l * 8];

    f32x4 acc[4][4];
    #pragma unroll
    for (int i = 0; i < 4; ++i)
        #pragma unroll
        for (int j = 0; j < 4; ++j)
            acc[i][j] = (f32x4){0.f, 0.f, 0.f, 0.f};

    for (int k0 = 0; k0 < K; k0 += BK) {
        gld16(Ag + k0,                  Asd);
        gld16(Ag + (size_t)16 * K + k0, Asd + 512);
        gld16(Bg + k0,                  Bsd);
        gld16(Bg + (size_t)16 * K + k0, Bsd + 512);
        __syncthreads();

        bf16x8 af[4], bfr[4];
        #pragma unroll
        for (int i = 0; i < 4; ++i)
            af[i] = *(const bf16x8*)&As[(wm + i * 16 + lr) * BK + lq * 8];
        #pragma unroll
        for (int j = 0; j < 4; ++j)
            bfr[j] = *(const bf16x8*)&Bs[(wn + j * 16 + lr) * BK + lq * 8];

        #pragma unroll
        for (int i = 0; i < 4; ++i)
            #pragma unroll
            for (int j = 0; j < 4; ++j)
                acc[i][j] = __builtin_amdgcn_mfma_f32_16x16x32_bf16(
                    af[i], bfr[j], acc[i][j], 0, 0, 0);
        __syncthreads();
    }

    // fused scan epilogue. tile col c<64 = P_{n0+c}, c>=64 = Q_{n0+c-64}
    const int n0  = cb * 64;
    const int seg = tid >> 6;        // == wave id
    const int nl  = tid & 63;
    const int n   = n0 + nl;
    const float bdv = bd[n], biv = bi[n];
    const float spA = softplus_f(A_log[n]);

    for (int bl = 0; bl < 2; ++bl) {
        if (bl) __syncthreads();     // previous batch's Ct reads done
        if ((w >> 1) == bl) {        // waves holding rows of batch bl
            #pragma unroll
            for (int i = 0; i < 4; ++i)
                #pragma unroll
                for (int j = 0; j < 4; ++j)
                    #pragma unroll
                    for (int r = 0; r < 4; ++r)
                        Ct[i * 16 + lq * 4 + r][wn + j * 16 + lr] = acc[i][j][r];
        }
        __syncthreads();

        // local 16-step segment: dec/drv written back in place
        float a = 1.f, hl = 0.f;
        #pragma unroll
        for (int s2 = 0; s2 < 16; ++s2) {
            const int s = seg * 16 + s2;
            const float delta = softplus_f(Ct[s][nl] + bdv);
            const float d  = __expf(-delta * spA);
            const float gv = delta * (Ct[s][64 + nl] + biv);
            Ct[s][nl] = d; Ct[s][64 + nl] = gv;
            a *= d; hl = d * hl + gv;
        }
        grp[seg][nl] = make_float2(a, hl);
        __syncthreads();

        float h = 0.f;
        for (int j = 0; j < seg; ++j) {   // wave-uniform trip count
            const float2 sv = grp[j][nl];
            h = sv.x * h + sv.y;
        }

        const int b = 2 * rb + bl;
        u16* hout = hsb + ((size_t)b * SHOTS + seg * 16) * SDIM + n;
        #pragma unroll
        for (int s2 = 0; s2 < 16; ++s2) {
            const int s = seg * 16 + s2;
            h = Ct[s][nl] * h + Ct[s][64 + nl];
            hout[(size_t)s2 * SDIM] = f2bf(h);
        }
        if (seg == 3) stateb[(size_t)b * SDIM + n] = h;
    }
}

// ---------------------------------------------------------------------------
// gemm_hidden: hidden = hs @ Wo^T + bo + cs, with cs = state @ Ws + bs
// computed INLINE after the K-loop (k-quartered matvec, ushort4 loads,
// partials through reused As LDS). Also writes csbuf (for final_kernel).
// BF16OUT: bf16 output (intermediate layer). POOL: per-batch row-sums.
// ---------------------------------------------------------------------------
template<bool BF16OUT, bool POOL>
__global__ __launch_bounds__(256)
void gemm_hidden(const u16* __restrict__ A, const u16* __restrict__ BT,
                 void* __restrict__ Cv, const float* __restrict__ bo,
                 const float* __restrict__ bs, const u16* __restrict__ Wsb,
                 const float* __restrict__ stateb, float* __restrict__ pooled,
                 float* __restrict__ csbuf, int CB)
{
    __shared__ __align__(16) u16 As[BM * BK];   // 8 KiB (reused: psumL)
    __shared__ __align__(16) u16 Bs[BN * BK];   // 8 KiB
    __shared__ float stL[512];                  // 2 KiB
    __shared__ float csL[2][128];               // 1 KiB

    const int tid = threadIdx.x;
    const int id  = blockIdx.x;
    const int xcd = id & 7, slot = id >> 3;
    const int rb = xcd + 8 * (slot / CB);
    const int cb = slot % CB;
    const int row0 = rb * BM, col0 = cb * BN;
    const int K = 256, ldc = DIM;
    const int b0 = row0 >> 6;                   // first of 2 batches (even)

    // state -> LDS early (written by gemm_pq_scan, stream-ordered)
    stL[tid]       = stateb[(size_t)b0 * SDIM + tid];
    stL[tid + 256] = stateb[(size_t)b0 * SDIM + tid + 256];

    const int l  = tid & 63;
    const int w  = tid >> 6;
    const int wm = (w >> 1) * 64, wn = (w & 1) * 64;
    const int lr = l & 15, lq = l >> 4;

    const int sg   = w * 2;
    const int srow = l >> 2;
    const int scol = (l & 3) * 8;
    const u16* Ag = A  + (size_t)(row0 + sg * 16 + srow) * K + scol;
    const u16* Bg = BT + (size_t)(col0 + sg * 16 + srow) * K + scol;
    u16* Asd = &As[sg * 512 + l * 8];
    u16* Bsd = &Bs[sg * 512 + l * 8];

    f32x4 acc[4][4];
    #pragma unroll
    for (int i = 0; i < 4; ++i)
        #pragma unroll
        for (int j = 0; j < 4; ++j)
            acc[i][j] = (f32x4){0.f, 0.f, 0.f, 0.f};

    for (int k0 = 0; k0 < K; k0 += BK) {
        gld16(Ag + k0,                  Asd);
        gld16(Ag + (size_t)16 * K + k0, Asd + 512);
        gld16(Bg + k0,                  Bsd);
        gld16(Bg + (size_t)16 * K + k0, Bsd + 512);
        __syncthreads();

        bf16x8 af[4], bfr[4];
        #pragma unroll
        for (int i = 0; i < 4; ++i)
            af[i] = *(const bf16x8*)&As[(wm + i * 16 + lr) * BK + lq * 8];
        #pragma unroll
        for (int j = 0; j < 4; ++j)
            bfr[j] = *(const bf16x8*)&Bs[(wn + j * 16 + lr) * BK + lq * 8];

        #pragma unroll
        for (int i = 0; i < 4; ++i)
            #pragma unroll
            for (int j = 0; j < 4; ++j)
                acc[i][j] = __builtin_amdgcn_mfma_f32_16x16x32_bf16(
                    af[i], bfr[j], acc[i][j], 0, 0, 0);
        __syncthreads();
    }

    // inline cs matvec: thread (kq = tid>>6, blc = (tid>>5)&1, cg = tid&31)
    {
        const int kq = tid >> 6, blc = (tid >> 5) & 1, cg = tid & 31;
        const int kb = kq * 64;
        f32x4 part = {0.f, 0.f, 0.f, 0.f};
        #pragma unroll 8
        for (int k = 0; k < 64; ++k) {
            const float sk = stL[blc * 256 + kb + k];
            const ushort4 wv = *(const ushort4*)
                &Wsb[(size_t)(kb + k) * DIM + col0 + cg * 4];
            part[0] += sk * bf2f(wv.x); part[1] += sk * bf2f(wv.y);
            part[2] += sk * bf2f(wv.z); part[3] += sk * bf2f(wv.w);
        }
        f32x4* psumL = (f32x4*)As;   // As is dead after the K-loop barrier
        psumL[tid] = part;
        __syncthreads();
        if (tid < 64) {
            const int bl2 = tid >> 5, cg2 = tid & 31;
            f32x4 s = psumL[bl2 * 32 + cg2];
            #pragma unroll
            for (int kq2 = 1; kq2 < 4; ++kq2)
                s += psumL[kq2 * 64 + bl2 * 32 + cg2];
            const float4 bv = *(const float4*)(bs + col0 + cg2 * 4);
            float4 o;
            o.x = s[0] + bv.x; o.y = s[1] + bv.y;
            o.z = s[2] + bv.z; o.w = s[3] + bv.w;
            *(float4*)&csL[bl2][cg2 * 4] = o;
            *(float4*)(csbuf + (size_t)(b0 + bl2) * DIM + col0 + cg2 * 4) = o;
        }
        __syncthreads();
    }

    // epilogue: C/D layout col=lane&15, row=quad*4+reg
    float psum[4] = {0.f, 0.f, 0.f, 0.f};
    #pragma unroll
    for (int i = 0; i < 4; ++i) {
        const int grow = row0 + wm + i * 16 + lq * 4;
        const int bl = (grow >> 6) & 1;
        #pragma unroll
        for (int j = 0; j < 4; ++j) {
            const int gcol = col0 + wn + j * 16 + lr;
            const float addv = bo[gcol] + csL[bl][gcol - col0];
            #pragma unroll
            for (int r = 0; r < 4; ++r) {
                const float val = acc[i][j][r] + addv;
                if (BF16OUT) ((u16*)Cv)[(size_t)(grow + r) * ldc + gcol] = f2bf(val);
                else         ((float*)Cv)[(size_t)(grow + r) * ldc + gcol] = val;
                if (POOL) psum[j] += val;
            }
        }
    }
    if (POOL) {
        const int batch_w = (row0 + wm) >> 6;
        #pragma unroll
        for (int j = 0; j < 4; ++j) {
            float v = psum[j];
            v += __shfl_xor(v, 16, 64);
            v += __shfl_xor(v, 32, 64);
            if (lq == 0)
                pooled[(size_t)batch_w * DIM + col0 + wn + j * 16 + lr] = v;
        }
    }
}

// ---------------------------------------------------------------------------
// final_kernel: pooled(sum) -> mean, + class_state, LayerNorm. ~2 MB traffic.
// ---------------------------------------------------------------------------
__global__ __launch_bounds__(1024)
void final_kernel(const float* __restrict__ pooled, const float* __restrict__ cs,
                  const float* __restrict__ gamma, const float* __restrict__ beta,
                  float* __restrict__ out)
{
    const int b = blockIdx.x;
    const int d = threadIdx.x;

    const float p = cs[(size_t)b * DIM + d]
                  + pooled[(size_t)b * DIM + d] * (1.f / SHOTS);

    __shared__ float rsum[1024], rsq[1024];
    rsum[d] = p; rsq[d] = p * p;
    __syncthreads();
    for (int off = 512; off > 0; off >>= 1) {
        if (d < off) { rsum[d] += rsum[d + off]; rsq[d] += rsq[d + off]; }
        __syncthreads();
    }
    const float mu  = rsum[0] * (1.f / DIM);
    const float var = rsq[0] * (1.f / DIM) - mu * mu;
    const float inv = rsqrtf(var + 1e-5f);

    out[(size_t)b * DIM + d] = (p - mu) * inv * gamma[d] + beta[d];
}

// ---------------------------------------------------------------------------

extern "C" void kernel_launch(void* const* d_in, const int* in_sizes, int n_in,
                              void* d_out, int out_size, void* d_ws, size_t ws_size,
                              hipStream_t stream)
{
    const float* X0    = (const float*)d_in[0];
    const float* Wd    = (const float*)d_in[1];
    const float* bd    = (const float*)d_in[2];
    const float* Wi    = (const float*)d_in[3];
    const float* bi    = (const float*)d_in[4];
    const float* A_log = (const float*)d_in[5];
    const float* Wo    = (const float*)d_in[6];
    const float* bo    = (const float*)d_in[7];
    const float* Ws    = (const float*)d_in[8];
    const float* bs    = (const float*)d_in[9];
    const float* gamma = (const float*)d_in[10];
    const float* beta  = (const float*)d_in[11];

    float* out_cr     = (float*)d_out;                  // [BATCH, DIM]
    float* out_hidden = out_cr + (size_t)BATCH * DIM;   // [BATCH, SHOTS, DIM] fp32

    // Xbf (bf16 activations) lives in the out_hidden region as scratch; it is
    // dead before the layer-1 hidden GEMM performs the fp32 out_hidden write.
    u16* Xbf = (u16*)out_hidden;

    // ws layout: ~15 MB <= proven 51.6 MB footprint (PQ buffer eliminated)
    char* w = (char*)d_ws;
    float*  csbuf  = (float*)w;  w += (size_t)BATCH * DIM * 4;          //  1.05 MB
    float*  pooled = (float*)w;  w += (size_t)BATCH * DIM * 4;          //  1.05 MB
    float*  stateb = (float*)w;  w += (size_t)BATCH * SDIM * 4;         //  0.26 MB
    u16*    hsb    = (u16*)w;    w += (size_t)M_TOT * SDIM * 2;         //  8.39 MB
    u16*    WcombT = (u16*)w;    w += (size_t)DEPTH * 512 * 1024 * 2;   //  2.10 MB
    u16*    WoT    = (u16*)w;    w += (size_t)DEPTH * 1024 * 256 * 2;   //  1.05 MB
    u16*    Wsb    = (u16*)w;    w += (size_t)DEPTH * SDIM * DIM * 2;   //  1.05 MB

    // all one-time conversions in ONE dispatch
    prep<<<2688, 256, 0, stream>>>(Wd, Wi, Wo, Ws, X0, WcombT, WoT, Wsb, Xbf);

    for (int l = 0; l < DEPTH; ++l) {
        // PQ GEMM + fused scan: Xbf @ [P|Q-permuted Wcomb] -> hsb, stateb
        gemm_pq_scan<<<512, 256, 0, stream>>>(
            Xbf, WcombT + (size_t)l * 512 * 1024,
            bd + l * SDIM, bi + l * SDIM, A_log + l * SDIM,
            hsb, stateb, 4);
        // hidden = hs @ Wo + bo + (state @ Ws + bs)  (cs inline)
        if (l < DEPTH - 1) {
            gemm_hidden<true, false><<<1024, 256, 0, stream>>>(
                hsb, WoT + (size_t)l * 1024 * 256, Xbf, bo + l * DIM,
                bs + l * DIM, Wsb + (size_t)l * SDIM * DIM, stateb,
                nullptr, csbuf, 8);
        } else {
            gemm_hidden<false, true><<<1024, 256, 0, stream>>>(
                hsb, WoT + (size_t)l * 1024 * 256, out_hidden, bo + l * DIM,
                bs + l * DIM, Wsb + (size_t)l * SDIM * DIM, stateb,
                pooled, csbuf, 8);
        }
    }
    final_kernel<<<BATCH, 1024, 0, stream>>>(pooled, csbuf, gamma, beta, out_cr);
}